// Round 12
// baseline (317.982 us; speedup 1.0000x reference)
//
#include <hip/hip_runtime.h>

typedef __attribute__((ext_vector_type(8))) short bf16x8;
typedef __attribute__((ext_vector_type(4))) float f32x4;

#define DEVI static __device__ __forceinline__

constexpr float NEGV = -1e9f;

DEVI unsigned short f2b(float f) {
  union { float f; unsigned int u; } c; c.f = f;
  unsigned int lsb = (c.u >> 16) & 1u;
  return (unsigned short)((c.u + 0x7fffu + lsb) >> 16);
}
DEVI float sb2f(short s) {
  union { unsigned int u; float f; } c;
  c.u = ((unsigned int)(unsigned short)s) << 16;
  return c.f;
}

// ---------------- mask canonicalization -> bit-packed [B*1024][32 u32] -----
__global__ void mask_detect(const unsigned int* __restrict__ m, int n, int* flag) {
  unsigned int v = 0;
  for (int i = blockIdx.x * blockDim.x + threadIdx.x; i < n; i += gridDim.x * blockDim.x)
    v |= m[i];
  if (v & ~1u) atomicOr(flag, 1);
}

__global__ void mask_canon_bits(const void* __restrict__ mraw, unsigned int* __restrict__ mb,
                                int nwords, const int* __restrict__ flag) {
  int i = blockIdx.x * blockDim.x + threadIdx.x;
  if (i >= nwords) return;
  bool isbytes = (*flag != 0);
  unsigned int out = 0;
  if (isbytes) {
    const unsigned int* p = (const unsigned int*)mraw + (size_t)i * 8;
    #pragma unroll
    for (int w = 0; w < 8; w++) {
      unsigned int bw = p[w];
      out |= ((bw & 1u) << (w * 4)) | (((bw >> 8) & 1u) << (w * 4 + 1)) |
             (((bw >> 16) & 1u) << (w * 4 + 2)) | (((bw >> 24) & 1u) << (w * 4 + 3));
    }
  } else {
    const int4* p = (const int4*)mraw + (size_t)i * 8;
    #pragma unroll
    for (int w = 0; w < 8; w++) {
      int4 v = p[w];
      out |= ((v.x != 0 ? 1u : 0u) << (w * 4)) | ((v.y != 0 ? 1u : 0u) << (w * 4 + 1)) |
             ((v.z != 0 ? 1u : 0u) << (w * 4 + 2)) | ((v.w != 0 ? 1u : 0u) << (w * 4 + 3));
    }
  }
  mb[i] = out;
}

// ---------------- LayerNorm over D=512, one row per block, bf16 out --------
__global__ __launch_bounds__(256) void ln_kernel(const float* __restrict__ q,
    const float* __restrict__ gamma, const float* __restrict__ beta,
    unsigned short* __restrict__ qn) {
  int row = blockIdx.x;
  int t = threadIdx.x;
  const float* x = q + (size_t)row * 512;
  float2 v = reinterpret_cast<const float2*>(x)[t];
  float s = v.x + v.y, s2 = v.x * v.x + v.y * v.y;
  #pragma unroll
  for (int o = 32; o; o >>= 1) { s += __shfl_xor(s, o); s2 += __shfl_xor(s2, o); }
  __shared__ float ls[4], ls2[4];
  int w = t >> 6;
  if ((t & 63) == 0) { ls[w] = s; ls2[w] = s2; }
  __syncthreads();
  float S = ls[0] + ls[1] + ls[2] + ls[3];
  float S2 = ls2[0] + ls2[1] + ls2[2] + ls2[3];
  float mu = S * (1.f / 512.f);
  float var = S2 * (1.f / 512.f) - mu * mu;
  float r = rsqrtf(var + 1e-6f);
  float g0 = gamma[t * 2], g1 = gamma[t * 2 + 1];
  float b0 = beta[t * 2], b1 = beta[t * 2 + 1];
  ushort2 o;
  o.x = f2b((v.x - mu) * r * g0 + b0);
  o.y = f2b((v.y - mu) * r * g1 + b1);
  reinterpret_cast<ushort2*>(qn + (size_t)row * 512)[t] = o;
}

// ---------------- GEMM: Y[M,N] = X[M,512] @ W[N,512]^T, fused cvt ----------
template<int MODE, bool CVX, bool CVW>
__global__ __launch_bounds__(256) void gemm_bt(
    const void* __restrict__ Xv,
    const void* __restrict__ Wv,
    void* __restrict__ Yv,
    float scale,
    const float* __restrict__ bias,
    const float* __restrict__ resid) {
  constexpr int LDT = 40;
  __shared__ __align__(16) unsigned short lA[64 * LDT];
  __shared__ __align__(16) unsigned short lB[64 * LDT];
  int t = threadIdx.x;
  int w = t >> 6, l = t & 63, lr = l & 15, lg = l >> 4;
  int mb = blockIdx.x * 64, nb = blockIdx.y * 64;
  f32x4 acc[4];
  #pragma unroll
  for (int n = 0; n < 4; n++) acc[n] = {0.f, 0.f, 0.f, 0.f};
  int sr = t >> 2, sc = (t & 3) * 8;
  for (int k0 = 0; k0 < 512; k0 += 32) {
    __syncthreads();
    if constexpr (CVX) {
      const float* src = (const float*)Xv + (size_t)(mb + sr) * 512 + k0 + sc;
      float4 x0 = *reinterpret_cast<const float4*>(src);
      float4 x1 = *reinterpret_cast<const float4*>(src + 4);
      ushort4 h0{f2b(x0.x), f2b(x0.y), f2b(x0.z), f2b(x0.w)};
      ushort4 h1{f2b(x1.x), f2b(x1.y), f2b(x1.z), f2b(x1.w)};
      *reinterpret_cast<ushort4*>(&lA[sr * LDT + sc]) = h0;
      *reinterpret_cast<ushort4*>(&lA[sr * LDT + sc + 4]) = h1;
    } else {
      *reinterpret_cast<float4*>(&lA[sr * LDT + sc]) =
          *reinterpret_cast<const float4*>((const unsigned short*)Xv + (size_t)(mb + sr) * 512 + k0 + sc);
    }
    if constexpr (CVW) {
      const float* src = (const float*)Wv + (size_t)(nb + sr) * 512 + k0 + sc;
      float4 x0 = *reinterpret_cast<const float4*>(src);
      float4 x1 = *reinterpret_cast<const float4*>(src + 4);
      ushort4 h0{f2b(x0.x), f2b(x0.y), f2b(x0.z), f2b(x0.w)};
      ushort4 h1{f2b(x1.x), f2b(x1.y), f2b(x1.z), f2b(x1.w)};
      *reinterpret_cast<ushort4*>(&lB[sr * LDT + sc]) = h0;
      *reinterpret_cast<ushort4*>(&lB[sr * LDT + sc + 4]) = h1;
    } else {
      *reinterpret_cast<float4*>(&lB[sr * LDT + sc]) =
          *reinterpret_cast<const float4*>((const unsigned short*)Wv + (size_t)(nb + sr) * 512 + k0 + sc);
    }
    __syncthreads();
    bf16x8 a = *reinterpret_cast<const bf16x8*>(&lA[(w * 16 + lr) * LDT + lg * 8]);
    #pragma unroll
    for (int n = 0; n < 4; n++) {
      bf16x8 bb = *reinterpret_cast<const bf16x8*>(&lB[(n * 16 + lr) * LDT + lg * 8]);
      acc[n] = __builtin_amdgcn_mfma_f32_16x16x32_bf16(a, bb, acc[n], 0, 0, 0);
    }
  }
  #pragma unroll
  for (int n = 0; n < 4; n++) {
    #pragma unroll
    for (int j = 0; j < 4; j++) {
      int m = mb + w * 16 + lg * 4 + j;
      int c = nb + n * 16 + lr;
      float val = acc[n][j] * scale;
      if constexpr (MODE == 0) {
        reinterpret_cast<unsigned short*>(Yv)[(size_t)m * 512 + c] = f2b(val);
      } else if constexpr (MODE == 1) {
        int bb_ = m >> 10, ll = m & 1023, hh = c >> 6, dd = c & 63;
        reinterpret_cast<unsigned short*>(Yv)[((size_t)((bb_ * 8 + hh) * 64 + dd)) * 1024 + ll] = f2b(val);
      } else {
        reinterpret_cast<float*>(Yv)[(size_t)m * 512 + c] =
            val + bias[c] + resid[(size_t)m * 512 + c];
      }
    }
  }
}

// ---------------- fused attention: direct L2 loads, ZERO in-loop barriers --
// 1024 blocks (XCD-clustered decode => K/V L2-resident), 256 thr = 4 waves.
__global__ __launch_bounds__(256) void attn_kernel(
    const unsigned short* __restrict__ qen,  // [8192,512] bf16 (pre-scaled 1/8)
    const unsigned short* __restrict__ qex,  // [8192,512] bf16 (pre-scaled 1/8)
    const unsigned short* __restrict__ kh,   // [8192,512] bf16
    const unsigned short* __restrict__ vhT,  // [B,H,64,1024] bf16
    const int* __restrict__ etype,           // [B,1024]
    const unsigned int* __restrict__ mbits,  // [B*1024][32] bit-packed mask
    float* __restrict__ attn_g,              // [B,H,1024,1024] f32
    unsigned short* __restrict__ pv_out) {   // [8192,512] bf16
  // XCD-clustered decode: 16 qt-blocks of one (h,b) land on one XCD.
  int lid = blockIdx.x;
  int xcd = lid & 7, slot = lid >> 3;
  int qt = slot & 15;
  int g = ((slot >> 4) << 3) | xcd;   // 0..63
  int h = g & 7, b = g >> 3;

  int t = threadIdx.x, w = t >> 6, l = t & 63, lr = l & 15, lg = l >> 4;
  __shared__ unsigned int ekbits[32];                 // event bit per k
  __shared__ unsigned int mkill[64 * 33];             // mask & evq, per q-row
  __shared__ __align__(16) unsigned short pbuf[4][16][40];  // wave-private P tile

  // Q fragments
  int qb = qt * 64 + w * 16;
  int qrowA = qb + lr;
  bool evA = etype[b * 1024 + qrowA] != 0;
  const unsigned short* qp = evA ? qen : qex;
  size_t qoff = (size_t)(b * 1024 + qrowA) * 512 + h * 64;
  bf16x8 a0 = *reinterpret_cast<const bf16x8*>(qp + qoff + lg * 8);
  bf16x8 a1 = *reinterpret_cast<const bf16x8*>(qp + qoff + 32 + lg * 8);

  // event bits for k range (32 words x 32 bits)
  if (t < 32) {
    unsigned int wdd = 0;
    const int4* ep = (const int4*)(etype + b * 1024 + t * 32);
    #pragma unroll
    for (int j4 = 0; j4 < 8; j4++) {
      int4 e = ep[j4];
      wdd |= ((e.x != 0 ? 1u : 0u) << (j4 * 4)) | ((e.y != 0 ? 1u : 0u) << (j4 * 4 + 1)) |
             ((e.z != 0 ? 1u : 0u) << (j4 * 4 + 2)) | ((e.w != 0 ? 1u : 0u) << (j4 * 4 + 3));
    }
    ekbits[t] = wdd;
  }
  // kill words: mask bit AND q-row-is-en
  {
    const unsigned int* mslice = mbits + ((size_t)(b * 1024 + qt * 64)) * 32;
    for (int i = t; i < 2048; i += 256) {
      int row = i >> 5, wd = i & 31;
      bool evq_row = etype[b * 1024 + qt * 64 + row] != 0;
      mkill[row * 33 + wd] = evq_row ? mslice[i] : 0u;
    }
  }
  __syncthreads();   // the ONLY block-wide barrier

  int qrc[4], qlc[4];
  #pragma unroll
  for (int j = 0; j < 4; j++) { qlc[j] = w * 16 + lg * 4 + j; qrc[j] = qt * 64 + qlc[j]; }

  // direct-load base pointers (L2-resident thanks to XCD clustering)
  const unsigned short* kptr = kh + ((size_t)b * 1024 + lr) * 512 + h * 64 + lg * 8;
  const unsigned short* vptr = vhT + ((size_t)((b * 8 + h) * 64) + lr) * 1024 + lg * 8;

  // ================= PASS 1: denominators (no barriers) =================
  float srun[4] = {0.f, 0.f, 0.f, 0.f};
  #pragma unroll 4
  for (int kt = 0; kt < 64; kt++) {
    const unsigned short* kp = kptr + (size_t)kt * 16 * 512;
    bf16x8 b0 = *reinterpret_cast<const bf16x8*>(kp);
    bf16x8 b1 = *reinterpret_cast<const bf16x8*>(kp + 32);
    f32x4 cc = {0.f, 0.f, 0.f, 0.f};
    cc = __builtin_amdgcn_mfma_f32_16x16x32_bf16(a0, b0, cc, 0, 0, 0);
    cc = __builtin_amdgcn_mfma_f32_16x16x32_bf16(a1, b1, cc, 0, 0, 0);
    int wcol = kt >> 1, bitpos = ((kt & 1) << 4) + lr;
    bool ekb = (ekbits[wcol] >> bitpos) & 1;
    #pragma unroll
    for (int j = 0; j < 4; j++) {
      bool mk = (mkill[qlc[j] * 33 + wcol] >> bitpos) & 1;
      float val = ekb ? (mk ? NEGV : cc[j]) : 0.f;
      srun[j] += __expf(val);
    }
  }
  float rS[4];
  #pragma unroll
  for (int j = 0; j < 4; j++) {
    float s = srun[j];
    s += __shfl_xor(s, 1); s += __shfl_xor(s, 2);
    s += __shfl_xor(s, 4); s += __shfl_xor(s, 8);
    rS[j] = 1.f / s;
  }

  // ================= PASS 2: attn write + PV (no barriers) =================
  f32x4 oacc[4];
  #pragma unroll
  for (int n = 0; n < 4; n++) oacc[n] = {0.f, 0.f, 0.f, 0.f};
  float* ag = attn_g + ((size_t)(b * 8 + h)) * 1024 * 1024;
  float* agrow = ag + (size_t)(qb + lr) * 1024 + lg * 8;

  #pragma unroll 2
  for (int kt = 0; kt < 64; kt++) {
    const unsigned short* kp = kptr + (size_t)kt * 16 * 512;
    bf16x8 b0 = *reinterpret_cast<const bf16x8*>(kp);
    bf16x8 b1 = *reinterpret_cast<const bf16x8*>(kp + 32);
    f32x4 cc = {0.f, 0.f, 0.f, 0.f};
    cc = __builtin_amdgcn_mfma_f32_16x16x32_bf16(a0, b0, cc, 0, 0, 0);
    cc = __builtin_amdgcn_mfma_f32_16x16x32_bf16(a1, b1, cc, 0, 0, 0);
    int wcol = kt >> 1, bitpos = ((kt & 1) << 4) + lr;
    bool ekb = (ekbits[wcol] >> bitpos) & 1;
    #pragma unroll
    for (int j = 0; j < 4; j++) {
      bool mk = (mkill[qlc[j] * 33 + wcol] >> bitpos) & 1;
      float val = ekb ? (mk ? NEGV : cc[j]) : 0.f;
      float p = __expf(val) * rS[j];
      pbuf[w][lg * 4 + j][((kt & 1) << 4) + lr] = f2b(p);
    }
    if (kt & 1) {
      int kc = kt >> 1;
      bf16x8 pa = *reinterpret_cast<const bf16x8*>(&pbuf[w][lr][lg * 8]);
      // coalesced attn store: row qb+lr, cols kc*32 + lg*8 .. +8
      f32x4 f0, f1;
      f0[0] = sb2f(pa[0]); f0[1] = sb2f(pa[1]); f0[2] = sb2f(pa[2]); f0[3] = sb2f(pa[3]);
      f1[0] = sb2f(pa[4]); f1[1] = sb2f(pa[5]); f1[2] = sb2f(pa[6]); f1[3] = sb2f(pa[7]);
      __builtin_nontemporal_store(f0, reinterpret_cast<f32x4*>(agrow + kc * 32));
      __builtin_nontemporal_store(f1, reinterpret_cast<f32x4*>(agrow + kc * 32 + 4));
      #pragma unroll
      for (int n = 0; n < 4; n++) {
        const unsigned short* vp = vptr + (size_t)n * 16 * 1024 + kc * 32;
        bf16x8 vb = *reinterpret_cast<const bf16x8*>(vp);
        oacc[n] = __builtin_amdgcn_mfma_f32_16x16x32_bf16(pa, vb, oacc[n], 0, 0, 0);
      }
    }
  }
  #pragma unroll
  for (int n = 0; n < 4; n++) {
    #pragma unroll
    for (int j = 0; j < 4; j++) {
      __builtin_nontemporal_store(f2b(oacc[n][j]),
          &pv_out[(size_t)(b * 1024 + qrc[j]) * 512 + h * 64 + n * 16 + lr]);
    }
  }
}

extern "C" void kernel_launch(void* const* d_in, const int* in_sizes, int n_in,
                              void* d_out, int out_size, void* d_ws, size_t ws_size,
                              hipStream_t stream) {
  (void)in_sizes; (void)n_in; (void)out_size; (void)ws_size;
  const float* q     = (const float*)d_in[0];
  const float* k     = (const float*)d_in[1];
  const float* v     = (const float*)d_in[2];
  const int* etype   = (const int*)d_in[3];
  const void* mask_raw = d_in[4];
  const float* w_qs  = (const float*)d_in[5];
  const float* w_ex  = (const float*)d_in[6];
  const float* w_ks  = (const float*)d_in[7];
  const float* w_vs  = (const float*)d_in[8];
  const float* w_fc  = (const float*)d_in[9];
  const float* b_fc  = (const float*)d_in[10];
  const float* gamma = (const float*)d_in[11];
  const float* beta  = (const float*)d_in[12];

  char* ws = (char*)d_ws;
  const size_t MB = 1024 * 1024;
  unsigned short* qn   = (unsigned short*)(ws);            // 8 MB bf16
  unsigned short* qen  = (unsigned short*)(ws + 8 * MB);
  unsigned short* qex  = (unsigned short*)(ws + 16 * MB);
  unsigned short* khb  = (unsigned short*)(ws + 24 * MB);
  unsigned short* vhT  = (unsigned short*)(ws + 32 * MB);
  unsigned short* ao   = (unsigned short*)(ws + 40 * MB);
  unsigned int* mbits  = (unsigned int*)(ws + 48 * MB);    // 1 MB
  int* mflag           = (int*)(ws + 49 * MB);

  float* outp = (float*)d_out;
  float* attn_g = outp + (size_t)8 * 1024 * 512;

  ln_kernel<<<8192, 256, 0, stream>>>(q, gamma, beta, qn);

  const int MASK_N = 8 * 1024 * 1024;
  hipMemsetAsync(mflag, 0, 4, stream);
  mask_detect<<<2048, 256, 0, stream>>>((const unsigned int*)mask_raw, MASK_N / 4, mflag);
  const int NWORDS = MASK_N / 32;
  mask_canon_bits<<<(NWORDS + 255) / 256, 256, 0, stream>>>(mask_raw, mbits, NWORDS, mflag);

  dim3 gg(128, 8);
  gemm_bt<0, false, true><<<gg, 256, 0, stream>>>(qn, w_qs, qen, 0.125f, nullptr, nullptr);
  gemm_bt<0, false, true><<<gg, 256, 0, stream>>>(qn, w_ex, qex, 0.125f, nullptr, nullptr);
  gemm_bt<0, true,  true><<<gg, 256, 0, stream>>>(k,  w_ks, khb, 1.0f, nullptr, nullptr);
  gemm_bt<1, true,  true><<<gg, 256, 0, stream>>>(v,  w_vs, vhT, 1.0f, nullptr, nullptr);

  attn_kernel<<<dim3(1024), 256, 0, stream>>>(qen, qex, khb, vhT, etype, mbits,
                                              attn_g, ao);

  gemm_bt<2, false, true><<<gg, 256, 0, stream>>>(ao, w_fc, outp, 1.0f, b_fc, q);
}

// Round 13
// 300.109 us; speedup vs baseline: 1.0596x; 1.0596x over previous
//
#include <hip/hip_runtime.h>

typedef __attribute__((ext_vector_type(8))) short bf16x8;
typedef __attribute__((ext_vector_type(4))) float f32x4;

#define DEVI static __device__ __forceinline__

constexpr float NEGV = -1e9f;

DEVI unsigned short f2b(float f) {
  union { float f; unsigned int u; } c; c.f = f;
  unsigned int lsb = (c.u >> 16) & 1u;
  return (unsigned short)((c.u + 0x7fffu + lsb) >> 16);
}
DEVI float sb2f(short s) {
  union { unsigned int u; float f; } c;
  c.u = ((unsigned int)(unsigned short)s) << 16;
  return c.f;
}

// ---------------- mask canonicalization -> bit-packed [B*1024][32 u32] -----
__global__ void mask_detect(const unsigned int* __restrict__ m, int n, int* flag) {
  unsigned int v = 0;
  for (int i = blockIdx.x * blockDim.x + threadIdx.x; i < n; i += gridDim.x * blockDim.x)
    v |= m[i];
  if (v & ~1u) atomicOr(flag, 1);
}

__global__ void mask_canon_bits(const void* __restrict__ mraw, unsigned int* __restrict__ mb,
                                int nwords, const int* __restrict__ flag) {
  int i = blockIdx.x * blockDim.x + threadIdx.x;
  if (i >= nwords) return;
  bool isbytes = (*flag != 0);
  unsigned int out = 0;
  if (isbytes) {
    const unsigned int* p = (const unsigned int*)mraw + (size_t)i * 8;
    #pragma unroll
    for (int w = 0; w < 8; w++) {
      unsigned int bw = p[w];
      out |= ((bw & 1u) << (w * 4)) | (((bw >> 8) & 1u) << (w * 4 + 1)) |
             (((bw >> 16) & 1u) << (w * 4 + 2)) | (((bw >> 24) & 1u) << (w * 4 + 3));
    }
  } else {
    const int4* p = (const int4*)mraw + (size_t)i * 8;
    #pragma unroll
    for (int w = 0; w < 8; w++) {
      int4 v = p[w];
      out |= ((v.x != 0 ? 1u : 0u) << (w * 4)) | ((v.y != 0 ? 1u : 0u) << (w * 4 + 1)) |
             ((v.z != 0 ? 1u : 0u) << (w * 4 + 2)) | ((v.w != 0 ? 1u : 0u) << (w * 4 + 3));
    }
  }
  mb[i] = out;
}

// ---------------- LayerNorm over D=512, one row per block, bf16 out --------
__global__ __launch_bounds__(256) void ln_kernel(const float* __restrict__ q,
    const float* __restrict__ gamma, const float* __restrict__ beta,
    unsigned short* __restrict__ qn) {
  int row = blockIdx.x;
  int t = threadIdx.x;
  const float* x = q + (size_t)row * 512;
  float2 v = reinterpret_cast<const float2*>(x)[t];
  float s = v.x + v.y, s2 = v.x * v.x + v.y * v.y;
  #pragma unroll
  for (int o = 32; o; o >>= 1) { s += __shfl_xor(s, o); s2 += __shfl_xor(s2, o); }
  __shared__ float ls[4], ls2[4];
  int w = t >> 6;
  if ((t & 63) == 0) { ls[w] = s; ls2[w] = s2; }
  __syncthreads();
  float S = ls[0] + ls[1] + ls[2] + ls[3];
  float S2 = ls2[0] + ls2[1] + ls2[2] + ls2[3];
  float mu = S * (1.f / 512.f);
  float var = S2 * (1.f / 512.f) - mu * mu;
  float r = rsqrtf(var + 1e-6f);
  float g0 = gamma[t * 2], g1 = gamma[t * 2 + 1];
  float b0 = beta[t * 2], b1 = beta[t * 2 + 1];
  ushort2 o;
  o.x = f2b((v.x - mu) * r * g0 + b0);
  o.y = f2b((v.y - mu) * r * g1 + b1);
  reinterpret_cast<ushort2*>(qn + (size_t)row * 512)[t] = o;
}

// ---------------- GEMM: Y[M,N] = X[M,512] @ W[N,512]^T, fused cvt ----------
template<int MODE, bool CVX, bool CVW>
__global__ __launch_bounds__(256) void gemm_bt(
    const void* __restrict__ Xv,
    const void* __restrict__ Wv,
    void* __restrict__ Yv,
    float scale,
    const float* __restrict__ bias,
    const float* __restrict__ resid) {
  constexpr int LDT = 40;
  __shared__ __align__(16) unsigned short lA[64 * LDT];
  __shared__ __align__(16) unsigned short lB[64 * LDT];
  int t = threadIdx.x;
  int w = t >> 6, l = t & 63, lr = l & 15, lg = l >> 4;
  int mb = blockIdx.x * 64, nb = blockIdx.y * 64;
  f32x4 acc[4];
  #pragma unroll
  for (int n = 0; n < 4; n++) acc[n] = {0.f, 0.f, 0.f, 0.f};
  int sr = t >> 2, sc = (t & 3) * 8;
  for (int k0 = 0; k0 < 512; k0 += 32) {
    __syncthreads();
    if constexpr (CVX) {
      const float* src = (const float*)Xv + (size_t)(mb + sr) * 512 + k0 + sc;
      float4 x0 = *reinterpret_cast<const float4*>(src);
      float4 x1 = *reinterpret_cast<const float4*>(src + 4);
      ushort4 h0{f2b(x0.x), f2b(x0.y), f2b(x0.z), f2b(x0.w)};
      ushort4 h1{f2b(x1.x), f2b(x1.y), f2b(x1.z), f2b(x1.w)};
      *reinterpret_cast<ushort4*>(&lA[sr * LDT + sc]) = h0;
      *reinterpret_cast<ushort4*>(&lA[sr * LDT + sc + 4]) = h1;
    } else {
      *reinterpret_cast<float4*>(&lA[sr * LDT + sc]) =
          *reinterpret_cast<const float4*>((const unsigned short*)Xv + (size_t)(mb + sr) * 512 + k0 + sc);
    }
    if constexpr (CVW) {
      const float* src = (const float*)Wv + (size_t)(nb + sr) * 512 + k0 + sc;
      float4 x0 = *reinterpret_cast<const float4*>(src);
      float4 x1 = *reinterpret_cast<const float4*>(src + 4);
      ushort4 h0{f2b(x0.x), f2b(x0.y), f2b(x0.z), f2b(x0.w)};
      ushort4 h1{f2b(x1.x), f2b(x1.y), f2b(x1.z), f2b(x1.w)};
      *reinterpret_cast<ushort4*>(&lB[sr * LDT + sc]) = h0;
      *reinterpret_cast<ushort4*>(&lB[sr * LDT + sc + 4]) = h1;
    } else {
      *reinterpret_cast<float4*>(&lB[sr * LDT + sc]) =
          *reinterpret_cast<const float4*>((const unsigned short*)Wv + (size_t)(nb + sr) * 512 + k0 + sc);
    }
    __syncthreads();
    bf16x8 a = *reinterpret_cast<const bf16x8*>(&lA[(w * 16 + lr) * LDT + lg * 8]);
    #pragma unroll
    for (int n = 0; n < 4; n++) {
      bf16x8 bb = *reinterpret_cast<const bf16x8*>(&lB[(n * 16 + lr) * LDT + lg * 8]);
      acc[n] = __builtin_amdgcn_mfma_f32_16x16x32_bf16(a, bb, acc[n], 0, 0, 0);
    }
  }
  #pragma unroll
  for (int n = 0; n < 4; n++) {
    #pragma unroll
    for (int j = 0; j < 4; j++) {
      int m = mb + w * 16 + lg * 4 + j;
      int c = nb + n * 16 + lr;
      float val = acc[n][j] * scale;
      if constexpr (MODE == 0) {
        reinterpret_cast<unsigned short*>(Yv)[(size_t)m * 512 + c] = f2b(val);
      } else if constexpr (MODE == 1) {
        int bb_ = m >> 10, ll = m & 1023, hh = c >> 6, dd = c & 63;
        reinterpret_cast<unsigned short*>(Yv)[((size_t)((bb_ * 8 + hh) * 64 + dd)) * 1024 + ll] = f2b(val);
      } else {
        reinterpret_cast<float*>(Yv)[(size_t)m * 512 + c] =
            val + bias[c] + resid[(size_t)m * 512 + c];
      }
    }
  }
}

// ---------------- fused attention: direct L2 loads, k-split 8-wave blocks --
// 1024 blocks (XCD-clustered decode), 512 thr = 8 waves; 64 q rows/block.
// Waves {w, w+4} share rows (w&3)*16.. and split k: khalf = w>>2.
__global__ __launch_bounds__(512, 8) void attn_kernel(
    const unsigned short* __restrict__ qen,  // [8192,512] bf16 (pre-scaled 1/8)
    const unsigned short* __restrict__ qex,  // [8192,512] bf16 (pre-scaled 1/8)
    const unsigned short* __restrict__ kh,   // [8192,512] bf16
    const unsigned short* __restrict__ vhT,  // [B,H,64,1024] bf16
    const int* __restrict__ etype,           // [B,1024]
    const unsigned int* __restrict__ mbits,  // [B*1024][32] bit-packed mask
    float* __restrict__ attn_g,              // [B,H,1024,1024] f32
    unsigned short* __restrict__ pv_out) {   // [8192,512] bf16
  // XCD-clustered decode: 16 qt-blocks of one (h,b) land on one XCD.
  int lid = blockIdx.x;
  int xcd = lid & 7, slot = lid >> 3;
  int qt = slot & 15;
  int g = ((slot >> 4) << 3) | xcd;   // 0..63
  int h = g & 7, b = g >> 3;

  int t = threadIdx.x, w = t >> 6, l = t & 63, lr = l & 15, lg = l >> 4;
  int rowgrp = w & 3, khalf = w >> 2;

  __shared__ unsigned int ekbits[32];                 // event bit per k
  __shared__ unsigned int mkill[64 * 33];             // mask & evq, per q-row
  __shared__ __align__(16) unsigned short pbuf[8][16][40];  // wave-private P tile
  __shared__ float sred[2][64];                       // per-half denom partials
  __shared__ __align__(16) float oshare[64][65];      // PV cross-half combine

  // Q fragments
  int qb = qt * 64 + rowgrp * 16;
  int qrowA = qb + lr;
  bool evA = etype[b * 1024 + qrowA] != 0;
  const unsigned short* qp = evA ? qen : qex;
  size_t qoff = (size_t)(b * 1024 + qrowA) * 512 + h * 64;
  bf16x8 a0 = *reinterpret_cast<const bf16x8*>(qp + qoff + lg * 8);
  bf16x8 a1 = *reinterpret_cast<const bf16x8*>(qp + qoff + 32 + lg * 8);

  // event bits for k range (32 words x 32 bits)
  if (t < 32) {
    unsigned int wdd = 0;
    const int4* ep = (const int4*)(etype + b * 1024 + t * 32);
    #pragma unroll
    for (int j4 = 0; j4 < 8; j4++) {
      int4 e = ep[j4];
      wdd |= ((e.x != 0 ? 1u : 0u) << (j4 * 4)) | ((e.y != 0 ? 1u : 0u) << (j4 * 4 + 1)) |
             (((e.z != 0 ? 1u : 0u)) << (j4 * 4 + 2)) | ((e.w != 0 ? 1u : 0u) << (j4 * 4 + 3));
    }
    ekbits[t] = wdd;
  }
  // kill words: mask bit AND q-row-is-en
  {
    const unsigned int* mslice = mbits + ((size_t)(b * 1024 + qt * 64)) * 32;
    for (int i = t; i < 2048; i += 512) {
      int row = i >> 5, wd = i & 31;
      bool evq_row = etype[b * 1024 + qt * 64 + row] != 0;
      mkill[row * 33 + wd] = evq_row ? mslice[i] : 0u;
    }
  }
  __syncthreads();

  int qrc[4], qlc[4];
  #pragma unroll
  for (int j = 0; j < 4; j++) { qlc[j] = rowgrp * 16 + lg * 4 + j; qrc[j] = qt * 64 + qlc[j]; }

  // direct-load base pointers (L2-resident thanks to XCD clustering)
  const unsigned short* kptr = kh + ((size_t)b * 1024 + khalf * 512 + lr) * 512 + h * 64 + lg * 8;
  const unsigned short* vptr = vhT + ((size_t)((b * 8 + h) * 64) + lr) * 1024 + khalf * 512 + lg * 8;

  // ================= PASS 1: denominators (no in-loop barriers) ===========
  float srun[4] = {0.f, 0.f, 0.f, 0.f};
  #pragma unroll 4
  for (int kt2 = 0; kt2 < 32; kt2++) {
    const unsigned short* kp = kptr + (size_t)kt2 * 16 * 512;
    bf16x8 b0 = *reinterpret_cast<const bf16x8*>(kp);
    bf16x8 b1 = *reinterpret_cast<const bf16x8*>(kp + 32);
    f32x4 cc = {0.f, 0.f, 0.f, 0.f};
    cc = __builtin_amdgcn_mfma_f32_16x16x32_bf16(a0, b0, cc, 0, 0, 0);
    cc = __builtin_amdgcn_mfma_f32_16x16x32_bf16(a1, b1, cc, 0, 0, 0);
    int wcol = khalf * 16 + (kt2 >> 1), bitpos = ((kt2 & 1) << 4) + lr;
    bool ekb = (ekbits[wcol] >> bitpos) & 1;
    #pragma unroll
    for (int j = 0; j < 4; j++) {
      bool mk = (mkill[qlc[j] * 33 + wcol] >> bitpos) & 1;
      float val = ekb ? (mk ? NEGV : cc[j]) : 0.f;
      srun[j] += __expf(val);
    }
  }
  #pragma unroll
  for (int j = 0; j < 4; j++) {
    float s = srun[j];
    s += __shfl_xor(s, 1); s += __shfl_xor(s, 2);
    s += __shfl_xor(s, 4); s += __shfl_xor(s, 8);
    if (lr == 0) sred[khalf][qlc[j]] = s;
  }
  __syncthreads();
  float rS[4];
  #pragma unroll
  for (int j = 0; j < 4; j++) rS[j] = 1.f / (sred[0][qlc[j]] + sred[1][qlc[j]]);

  // ================= PASS 2: attn write + PV (no in-loop barriers) ========
  f32x4 oacc[4];
  #pragma unroll
  for (int n = 0; n < 4; n++) oacc[n] = {0.f, 0.f, 0.f, 0.f};
  float* ag = attn_g + ((size_t)(b * 8 + h)) * 1024 * 1024;
  float* agrow = ag + (size_t)(qb + lr) * 1024 + khalf * 512 + lg * 8;

  #pragma unroll 2
  for (int kt2 = 0; kt2 < 32; kt2++) {
    const unsigned short* kp = kptr + (size_t)kt2 * 16 * 512;
    bf16x8 b0 = *reinterpret_cast<const bf16x8*>(kp);
    bf16x8 b1 = *reinterpret_cast<const bf16x8*>(kp + 32);
    f32x4 cc = {0.f, 0.f, 0.f, 0.f};
    cc = __builtin_amdgcn_mfma_f32_16x16x32_bf16(a0, b0, cc, 0, 0, 0);
    cc = __builtin_amdgcn_mfma_f32_16x16x32_bf16(a1, b1, cc, 0, 0, 0);
    int wcol = khalf * 16 + (kt2 >> 1), bitpos = ((kt2 & 1) << 4) + lr;
    bool ekb = (ekbits[wcol] >> bitpos) & 1;
    #pragma unroll
    for (int j = 0; j < 4; j++) {
      bool mk = (mkill[qlc[j] * 33 + wcol] >> bitpos) & 1;
      float val = ekb ? (mk ? NEGV : cc[j]) : 0.f;
      float p = __expf(val) * rS[j];
      pbuf[w][lg * 4 + j][((kt2 & 1) << 4) + lr] = f2b(p);
    }
    if (kt2 & 1) {
      int kc = kt2 >> 1;
      bf16x8 pa = *reinterpret_cast<const bf16x8*>(&pbuf[w][lr][lg * 8]);
      f32x4 f0, f1;
      f0[0] = sb2f(pa[0]); f0[1] = sb2f(pa[1]); f0[2] = sb2f(pa[2]); f0[3] = sb2f(pa[3]);
      f1[0] = sb2f(pa[4]); f1[1] = sb2f(pa[5]); f1[2] = sb2f(pa[6]); f1[3] = sb2f(pa[7]);
      __builtin_nontemporal_store(f0, reinterpret_cast<f32x4*>(agrow + kc * 32));
      __builtin_nontemporal_store(f1, reinterpret_cast<f32x4*>(agrow + kc * 32 + 4));
      #pragma unroll
      for (int n = 0; n < 4; n++) {
        const unsigned short* vp = vptr + (size_t)n * 16 * 1024 + kc * 32;
        bf16x8 vb = *reinterpret_cast<const bf16x8*>(vp);
        oacc[n] = __builtin_amdgcn_mfma_f32_16x16x32_bf16(pa, vb, oacc[n], 0, 0, 0);
      }
    }
  }

  // cross-half PV combine
  if (khalf == 0) {
    #pragma unroll
    for (int n = 0; n < 4; n++)
      #pragma unroll
      for (int j = 0; j < 4; j++)
        oshare[qlc[j]][n * 16 + lr] = oacc[n][j];
  }
  __syncthreads();
  if (khalf == 1) {
    #pragma unroll
    for (int n = 0; n < 4; n++) {
      #pragma unroll
      for (int j = 0; j < 4; j++) {
        float v = oacc[n][j] + oshare[qlc[j]][n * 16 + lr];
        __builtin_nontemporal_store(f2b(v),
            &pv_out[(size_t)(b * 1024 + qrc[j]) * 512 + h * 64 + n * 16 + lr]);
      }
    }
  }
}

extern "C" void kernel_launch(void* const* d_in, const int* in_sizes, int n_in,
                              void* d_out, int out_size, void* d_ws, size_t ws_size,
                              hipStream_t stream) {
  (void)in_sizes; (void)n_in; (void)out_size; (void)ws_size;
  const float* q     = (const float*)d_in[0];
  const float* k     = (const float*)d_in[1];
  const float* v     = (const float*)d_in[2];
  const int* etype   = (const int*)d_in[3];
  const void* mask_raw = d_in[4];
  const float* w_qs  = (const float*)d_in[5];
  const float* w_ex  = (const float*)d_in[6];
  const float* w_ks  = (const float*)d_in[7];
  const float* w_vs  = (const float*)d_in[8];
  const float* w_fc  = (const float*)d_in[9];
  const float* b_fc  = (const float*)d_in[10];
  const float* gamma = (const float*)d_in[11];
  const float* beta  = (const float*)d_in[12];

  char* ws = (char*)d_ws;
  const size_t MB = 1024 * 1024;
  unsigned short* qn   = (unsigned short*)(ws);            // 8 MB bf16
  unsigned short* qen  = (unsigned short*)(ws + 8 * MB);
  unsigned short* qex  = (unsigned short*)(ws + 16 * MB);
  unsigned short* khb  = (unsigned short*)(ws + 24 * MB);
  unsigned short* vhT  = (unsigned short*)(ws + 32 * MB);
  unsigned short* ao   = (unsigned short*)(ws + 40 * MB);
  unsigned int* mbits  = (unsigned int*)(ws + 48 * MB);    // 1 MB
  int* mflag           = (int*)(ws + 49 * MB);

  float* outp = (float*)d_out;
  float* attn_g = outp + (size_t)8 * 1024 * 512;

  ln_kernel<<<8192, 256, 0, stream>>>(q, gamma, beta, qn);

  const int MASK_N = 8 * 1024 * 1024;
  hipMemsetAsync(mflag, 0, 4, stream);
  mask_detect<<<2048, 256, 0, stream>>>((const unsigned int*)mask_raw, MASK_N / 4, mflag);
  const int NWORDS = MASK_N / 32;
  mask_canon_bits<<<(NWORDS + 255) / 256, 256, 0, stream>>>(mask_raw, mbits, NWORDS, mflag);

  dim3 gg(128, 8);
  gemm_bt<0, false, true><<<gg, 256, 0, stream>>>(qn, w_qs, qen, 0.125f, nullptr, nullptr);
  gemm_bt<0, false, true><<<gg, 256, 0, stream>>>(qn, w_ex, qex, 0.125f, nullptr, nullptr);
  gemm_bt<0, true,  true><<<gg, 256, 0, stream>>>(k,  w_ks, khb, 1.0f, nullptr, nullptr);
  gemm_bt<1, true,  true><<<gg, 256, 0, stream>>>(v,  w_vs, vhT, 1.0f, nullptr, nullptr);

  attn_kernel<<<dim3(1024), 512, 0, stream>>>(qen, qex, khb, vhT, etype, mbits,
                                              attn_g, ao);

  gemm_bt<2, false, true><<<gg, 256, 0, stream>>>(ao, w_fc, outp, 1.0f, b_fc, q);
}

// Round 14
// 260.761 us; speedup vs baseline: 1.2194x; 1.1509x over previous
//
#include <hip/hip_runtime.h>

typedef __attribute__((ext_vector_type(8))) short bf16x8;
typedef __attribute__((ext_vector_type(4))) float f32x4;

#define DEVI static __device__ __forceinline__

constexpr float NEGV = -1e9f;

DEVI unsigned short f2b(float f) {
  union { float f; unsigned int u; } c; c.f = f;
  unsigned int lsb = (c.u >> 16) & 1u;
  return (unsigned short)((c.u + 0x7fffu + lsb) >> 16);
}
DEVI float sb2f(short s) {
  union { unsigned int u; float f; } c;
  c.u = ((unsigned int)(unsigned short)s) << 16;
  return c.f;
}

DEVI void gload16(const unsigned short* g, unsigned short* l) {
  __builtin_amdgcn_global_load_lds(
      (const __attribute__((address_space(1))) unsigned int*)g,
      (__attribute__((address_space(3))) unsigned int*)l, 16, 0, 0);
}

// ---------------- mask canonicalization -> bit-packed [B*1024][32 u32] -----
__global__ void mask_detect(const unsigned int* __restrict__ m, int n, int* flag) {
  unsigned int v = 0;
  for (int i = blockIdx.x * blockDim.x + threadIdx.x; i < n; i += gridDim.x * blockDim.x)
    v |= m[i];
  if (v & ~1u) atomicOr(flag, 1);
}

__global__ void mask_canon_bits(const void* __restrict__ mraw, unsigned int* __restrict__ mb,
                                int nwords, const int* __restrict__ flag) {
  int i = blockIdx.x * blockDim.x + threadIdx.x;
  if (i >= nwords) return;
  bool isbytes = (*flag != 0);
  unsigned int out = 0;
  if (isbytes) {
    const unsigned int* p = (const unsigned int*)mraw + (size_t)i * 8;
    #pragma unroll
    for (int w = 0; w < 8; w++) {
      unsigned int bw = p[w];
      out |= ((bw & 1u) << (w * 4)) | (((bw >> 8) & 1u) << (w * 4 + 1)) |
             (((bw >> 16) & 1u) << (w * 4 + 2)) | (((bw >> 24) & 1u) << (w * 4 + 3));
    }
  } else {
    const int4* p = (const int4*)mraw + (size_t)i * 8;
    #pragma unroll
    for (int w = 0; w < 8; w++) {
      int4 v = p[w];
      out |= ((v.x != 0 ? 1u : 0u) << (w * 4)) | ((v.y != 0 ? 1u : 0u) << (w * 4 + 1)) |
             ((v.z != 0 ? 1u : 0u) << (w * 4 + 2)) | ((v.w != 0 ? 1u : 0u) << (w * 4 + 3));
    }
  }
  mb[i] = out;
}

// ---------------- LayerNorm over D=512, one row per block, bf16 out --------
__global__ __launch_bounds__(256) void ln_kernel(const float* __restrict__ q,
    const float* __restrict__ gamma, const float* __restrict__ beta,
    unsigned short* __restrict__ qn) {
  int row = blockIdx.x;
  int t = threadIdx.x;
  const float* x = q + (size_t)row * 512;
  float2 v = reinterpret_cast<const float2*>(x)[t];
  float s = v.x + v.y, s2 = v.x * v.x + v.y * v.y;
  #pragma unroll
  for (int o = 32; o; o >>= 1) { s += __shfl_xor(s, o); s2 += __shfl_xor(s2, o); }
  __shared__ float ls[4], ls2[4];
  int w = t >> 6;
  if ((t & 63) == 0) { ls[w] = s; ls2[w] = s2; }
  __syncthreads();
  float S = ls[0] + ls[1] + ls[2] + ls[3];
  float S2 = ls2[0] + ls2[1] + ls2[2] + ls2[3];
  float mu = S * (1.f / 512.f);
  float var = S2 * (1.f / 512.f) - mu * mu;
  float r = rsqrtf(var + 1e-6f);
  float g0 = gamma[t * 2], g1 = gamma[t * 2 + 1];
  float b0 = beta[t * 2], b1 = beta[t * 2 + 1];
  ushort2 o;
  o.x = f2b((v.x - mu) * r * g0 + b0);
  o.y = f2b((v.y - mu) * r * g1 + b1);
  reinterpret_cast<ushort2*>(qn + (size_t)row * 512)[t] = o;
}

// ---------------- GEMM: Y[M,N] = X[M,512] @ W[N,512]^T, fused cvt ----------
template<int MODE, bool CVX, bool CVW>
__global__ __launch_bounds__(256) void gemm_bt(
    const void* __restrict__ Xv,
    const void* __restrict__ Wv,
    void* __restrict__ Yv,
    float scale,
    const float* __restrict__ bias,
    const float* __restrict__ resid) {
  constexpr int LDT = 40;
  __shared__ __align__(16) unsigned short lA[64 * LDT];
  __shared__ __align__(16) unsigned short lB[64 * LDT];
  int t = threadIdx.x;
  int w = t >> 6, l = t & 63, lr = l & 15, lg = l >> 4;
  int mb = blockIdx.x * 64, nb = blockIdx.y * 64;
  f32x4 acc[4];
  #pragma unroll
  for (int n = 0; n < 4; n++) acc[n] = {0.f, 0.f, 0.f, 0.f};
  int sr = t >> 2, sc = (t & 3) * 8;
  for (int k0 = 0; k0 < 512; k0 += 32) {
    __syncthreads();
    if constexpr (CVX) {
      const float* src = (const float*)Xv + (size_t)(mb + sr) * 512 + k0 + sc;
      float4 x0 = *reinterpret_cast<const float4*>(src);
      float4 x1 = *reinterpret_cast<const float4*>(src + 4);
      ushort4 h0{f2b(x0.x), f2b(x0.y), f2b(x0.z), f2b(x0.w)};
      ushort4 h1{f2b(x1.x), f2b(x1.y), f2b(x1.z), f2b(x1.w)};
      *reinterpret_cast<ushort4*>(&lA[sr * LDT + sc]) = h0;
      *reinterpret_cast<ushort4*>(&lA[sr * LDT + sc + 4]) = h1;
    } else {
      *reinterpret_cast<float4*>(&lA[sr * LDT + sc]) =
          *reinterpret_cast<const float4*>((const unsigned short*)Xv + (size_t)(mb + sr) * 512 + k0 + sc);
    }
    if constexpr (CVW) {
      const float* src = (const float*)Wv + (size_t)(nb + sr) * 512 + k0 + sc;
      float4 x0 = *reinterpret_cast<const float4*>(src);
      float4 x1 = *reinterpret_cast<const float4*>(src + 4);
      ushort4 h0{f2b(x0.x), f2b(x0.y), f2b(x0.z), f2b(x0.w)};
      ushort4 h1{f2b(x1.x), f2b(x1.y), f2b(x1.z), f2b(x1.w)};
      *reinterpret_cast<ushort4*>(&lB[sr * LDT + sc]) = h0;
      *reinterpret_cast<ushort4*>(&lB[sr * LDT + sc + 4]) = h1;
    } else {
      *reinterpret_cast<float4*>(&lB[sr * LDT + sc]) =
          *reinterpret_cast<const float4*>((const unsigned short*)Wv + (size_t)(nb + sr) * 512 + k0 + sc);
    }
    __syncthreads();
    bf16x8 a = *reinterpret_cast<const bf16x8*>(&lA[(w * 16 + lr) * LDT + lg * 8]);
    #pragma unroll
    for (int n = 0; n < 4; n++) {
      bf16x8 bb = *reinterpret_cast<const bf16x8*>(&lB[(n * 16 + lr) * LDT + lg * 8]);
      acc[n] = __builtin_amdgcn_mfma_f32_16x16x32_bf16(a, bb, acc[n], 0, 0, 0);
    }
  }
  #pragma unroll
  for (int n = 0; n < 4; n++) {
    #pragma unroll
    for (int j = 0; j < 4; j++) {
      int m = mb + w * 16 + lg * 4 + j;
      int c = nb + n * 16 + lr;
      float val = acc[n][j] * scale;
      if constexpr (MODE == 0) {
        reinterpret_cast<unsigned short*>(Yv)[(size_t)m * 512 + c] = f2b(val);
      } else if constexpr (MODE == 1) {
        int bb_ = m >> 10, ll = m & 1023, hh = c >> 6, dd = c & 63;
        reinterpret_cast<unsigned short*>(Yv)[((size_t)((bb_ * 8 + hh) * 64 + dd)) * 1024 + ll] = f2b(val);
      } else {
        reinterpret_cast<float*>(Yv)[(size_t)m * 512 + c] =
            val + bias[c] + resid[(size_t)m * 512 + c];
      }
    }
  }
}

// ---------------- fused attention (R7 structure, coalesced ag stores) ------
// grid (16, H=8, B=8), 256 threads = 4 waves; wave owns 16 q rows, full k.
__global__ __launch_bounds__(256) void attn_kernel(
    const unsigned short* __restrict__ qen,  // [8192,512] bf16 (pre-scaled 1/8)
    const unsigned short* __restrict__ qex,  // [8192,512] bf16 (pre-scaled 1/8)
    const unsigned short* __restrict__ kh,   // [8192,512] bf16
    const unsigned short* __restrict__ vhT,  // [B,H,64,1024] bf16
    const int* __restrict__ etype,           // [B,1024]
    const unsigned int* __restrict__ mbits,  // [B*1024][32] bit-packed mask
    float* __restrict__ attn_g,              // [B,H,1024,1024] f32
    unsigned short* __restrict__ pv_out) {   // [8192,512] bf16
  int qt = blockIdx.x, h = blockIdx.y, b = blockIdx.z;
  int t = threadIdx.x, w = t >> 6, l = t & 63, lr = l & 15, lg = l >> 4;
  __shared__ unsigned int ekbits[32];                 // event bit per k
  __shared__ unsigned int mkill[64 * 33];             // mask & evq, per q-row
  __shared__ __align__(16) unsigned short klds[2][2048]; // dbuf, 32r x 64c swz
  __shared__ __align__(16) unsigned short vlds[2][2048]; // dbuf, 64r x 32c swz
  __shared__ __align__(16) unsigned short pbuf[4][16][40];

  // Q fragments (pre-barrier, global only)
  int qb = qt * 64 + w * 16;
  int qrowA = qb + lr;
  bool evA = etype[b * 1024 + qrowA] != 0;
  const unsigned short* qp = evA ? qen : qex;
  size_t qoff = (size_t)(b * 1024 + qrowA) * 512 + h * 64;
  bf16x8 a0 = *reinterpret_cast<const bf16x8*>(qp + qoff + lg * 8);
  bf16x8 a1 = *reinterpret_cast<const bf16x8*>(qp + qoff + 32 + lg * 8);

  // event bits for k range (32 words x 32 bits)
  if (t < 32) {
    unsigned int wdd = 0;
    const int4* ep = (const int4*)(etype + b * 1024 + t * 32);
    #pragma unroll
    for (int j4 = 0; j4 < 8; j4++) {
      int4 e = ep[j4];
      wdd |= ((e.x != 0 ? 1u : 0u) << (j4 * 4)) | ((e.y != 0 ? 1u : 0u) << (j4 * 4 + 1)) |
             ((e.z != 0 ? 1u : 0u) << (j4 * 4 + 2)) | ((e.w != 0 ? 1u : 0u) << (j4 * 4 + 3));
    }
    ekbits[t] = wdd;
  }
  // kill words: mask bit AND q-row-is-en
  {
    const unsigned int* mslice = mbits + ((size_t)(b * 1024 + qt * 64)) * 32;
    for (int i = t; i < 2048; i += 256) {
      int row = i >> 5, wd = i & 31;
      bool evq_row = etype[b * 1024 + qt * 64 + row] != 0;
      mkill[row * 33 + wd] = evq_row ? mslice[i] : 0u;
    }
  }

  int qrc[4], qlc[4];
  #pragma unroll
  for (int j = 0; j < 4; j++) { qlc[j] = w * 16 + lg * 4 + j; qrc[j] = qt * 64 + qlc[j]; }

  // staging coords (gload_lds: per-wave base, HW adds lane*16)
  int srow = t >> 3, sb8 = t & 7;
  const unsigned short* kgsrc = kh + ((size_t)(b * 1024) + srow) * 512 + h * 64
                                + ((sb8 ^ (srow & 7)) << 3);
  unsigned short* kdst0 = &klds[0][(t & 192) * 8];
  unsigned short* kdst1 = &klds[1][(t & 192) * 8];
  int vrow = t >> 2, vb4 = t & 3;
  const unsigned short* vb_base = vhT + ((size_t)((b * 8 + h) * 64)) * 1024;
  const unsigned short* vgsrc = vb_base + (size_t)vrow * 1024 + ((vb4 ^ ((vrow >> 1) & 3)) << 3);
  unsigned short* vdst0 = &vlds[0][(t & 192) * 8];
  unsigned short* vdst1 = &vlds[1][(t & 192) * 8];

  // ================= PASS 1: denominators =================
  gload16(kgsrc, kdst0);
  __syncthreads();   // stage(chunk0) done + ekbits/mkill visible

  float srun[4] = {0.f, 0.f, 0.f, 0.f};
  for (int c = 0; c < 32; c++) {
    int cur = c & 1;
    if (c < 31) gload16(kgsrc + (size_t)(c + 1) * 32 * 512, cur ? kdst0 : kdst1);
    #pragma unroll
    for (int c2 = 0; c2 < 2; c2++) {
      int kt = c * 2 + c2;
      int row = c2 * 16 + lr, r7 = row & 7;
      bf16x8 b0 = *reinterpret_cast<const bf16x8*>(&klds[cur][row * 64 + ((lg ^ r7) << 3)]);
      bf16x8 b1 = *reinterpret_cast<const bf16x8*>(&klds[cur][row * 64 + (((4 + lg) ^ r7) << 3)]);
      f32x4 cc = {0.f, 0.f, 0.f, 0.f};
      cc = __builtin_amdgcn_mfma_f32_16x16x32_bf16(a0, b0, cc, 0, 0, 0);
      cc = __builtin_amdgcn_mfma_f32_16x16x32_bf16(a1, b1, cc, 0, 0, 0);
      int wcol = kt >> 1, bitpos = ((kt & 1) << 4) + lr;
      bool ekb = (ekbits[wcol] >> bitpos) & 1;
      #pragma unroll
      for (int j = 0; j < 4; j++) {
        bool mk = (mkill[qlc[j] * 33 + wcol] >> bitpos) & 1;
        float val = ekb ? (mk ? NEGV : cc[j]) : 0.f;
        srun[j] += __expf(val);
      }
    }
    __syncthreads();
  }
  float rS[4];
  #pragma unroll
  for (int j = 0; j < 4; j++) {
    float s = srun[j];
    s += __shfl_xor(s, 1); s += __shfl_xor(s, 2);
    s += __shfl_xor(s, 4); s += __shfl_xor(s, 8);
    rS[j] = 1.f / s;
  }

  // ================= PASS 2: attn write + PV =================
  f32x4 oacc[4];
  #pragma unroll
  for (int n = 0; n < 4; n++) oacc[n] = {0.f, 0.f, 0.f, 0.f};
  float* ag = attn_g + ((size_t)(b * 8 + h)) * 1024 * 1024;
  float* agrow = ag + (size_t)(qb + lr) * 1024 + lg * 8;

  gload16(kgsrc, kdst0);
  gload16(vgsrc, vdst0);
  __syncthreads();

  for (int c = 0; c < 32; c++) {
    int cur = c & 1;
    if (c < 31) {
      gload16(kgsrc + (size_t)(c + 1) * 32 * 512, cur ? kdst0 : kdst1);
      gload16(vgsrc + (size_t)(c + 1) * 32, cur ? vdst0 : vdst1);
    }
    #pragma unroll
    for (int c2 = 0; c2 < 2; c2++) {
      int kt = c * 2 + c2;
      int row = c2 * 16 + lr, r7 = row & 7;
      bf16x8 b0 = *reinterpret_cast<const bf16x8*>(&klds[cur][row * 64 + ((lg ^ r7) << 3)]);
      bf16x8 b1 = *reinterpret_cast<const bf16x8*>(&klds[cur][row * 64 + (((4 + lg) ^ r7) << 3)]);
      f32x4 cc = {0.f, 0.f, 0.f, 0.f};
      cc = __builtin_amdgcn_mfma_f32_16x16x32_bf16(a0, b0, cc, 0, 0, 0);
      cc = __builtin_amdgcn_mfma_f32_16x16x32_bf16(a1, b1, cc, 0, 0, 0);
      int wcol = kt >> 1, bitpos = ((kt & 1) << 4) + lr;
      bool ekb = (ekbits[wcol] >> bitpos) & 1;
      #pragma unroll
      for (int j = 0; j < 4; j++) {
        bool mk = (mkill[qlc[j] * 33 + wcol] >> bitpos) & 1;
        float val = ekb ? (mk ? NEGV : cc[j]) : 0.f;
        float p = __expf(val) * rS[j];
        pbuf[w][lg * 4 + j][(c2 << 4) + lr] = f2b(p);
      }
      if (c2) {
        bf16x8 pa = *reinterpret_cast<const bf16x8*>(&pbuf[w][lr][lg * 8]);
        // coalesced attn store: row qb+lr, cols c*32 + lg*8 .. +8
        f32x4 f0, f1;
        f0[0] = sb2f(pa[0]); f0[1] = sb2f(pa[1]); f0[2] = sb2f(pa[2]); f0[3] = sb2f(pa[3]);
        f1[0] = sb2f(pa[4]); f1[1] = sb2f(pa[5]); f1[2] = sb2f(pa[6]); f1[3] = sb2f(pa[7]);
        __builtin_nontemporal_store(f0, reinterpret_cast<f32x4*>(agrow + c * 32));
        __builtin_nontemporal_store(f1, reinterpret_cast<f32x4*>(agrow + c * 32 + 4));
        #pragma unroll
        for (int n = 0; n < 4; n++) {
          int vr = n * 16 + lr;
          int cb = (lg ^ ((vr >> 1) & 3)) << 3;
          bf16x8 vb = *reinterpret_cast<const bf16x8*>(&vlds[cur][vr * 32 + cb]);
          oacc[n] = __builtin_amdgcn_mfma_f32_16x16x32_bf16(pa, vb, oacc[n], 0, 0, 0);
        }
      }
    }
    __syncthreads();
  }
  #pragma unroll
  for (int n = 0; n < 4; n++) {
    #pragma unroll
    for (int j = 0; j < 4; j++) {
      __builtin_nontemporal_store(f2b(oacc[n][j]),
          &pv_out[(size_t)(b * 1024 + qrc[j]) * 512 + h * 64 + n * 16 + lr]);
    }
  }
}

extern "C" void kernel_launch(void* const* d_in, const int* in_sizes, int n_in,
                              void* d_out, int out_size, void* d_ws, size_t ws_size,
                              hipStream_t stream) {
  (void)in_sizes; (void)n_in; (void)out_size; (void)ws_size;
  const float* q     = (const float*)d_in[0];
  const float* k     = (const float*)d_in[1];
  const float* v     = (const float*)d_in[2];
  const int* etype   = (const int*)d_in[3];
  const void* mask_raw = d_in[4];
  const float* w_qs  = (const float*)d_in[5];
  const float* w_ex  = (const float*)d_in[6];
  const float* w_ks  = (const float*)d_in[7];
  const float* w_vs  = (const float*)d_in[8];
  const float* w_fc  = (const float*)d_in[9];
  const float* b_fc  = (const float*)d_in[10];
  const float* gamma = (const float*)d_in[11];
  const float* beta  = (const float*)d_in[12];

  char* ws = (char*)d_ws;
  const size_t MB = 1024 * 1024;
  unsigned short* qn   = (unsigned short*)(ws);            // 8 MB bf16
  unsigned short* qen  = (unsigned short*)(ws + 8 * MB);
  unsigned short* qex  = (unsigned short*)(ws + 16 * MB);
  unsigned short* khb  = (unsigned short*)(ws + 24 * MB);
  unsigned short* vhT  = (unsigned short*)(ws + 32 * MB);
  unsigned short* ao   = (unsigned short*)(ws + 40 * MB);
  unsigned int* mbits  = (unsigned int*)(ws + 48 * MB);    // 1 MB
  int* mflag           = (int*)(ws + 49 * MB);

  float* outp = (float*)d_out;
  float* attn_g = outp + (size_t)8 * 1024 * 512;

  ln_kernel<<<8192, 256, 0, stream>>>(q, gamma, beta, qn);

  const int MASK_N = 8 * 1024 * 1024;
  hipMemsetAsync(mflag, 0, 4, stream);
  mask_detect<<<2048, 256, 0, stream>>>((const unsigned int*)mask_raw, MASK_N / 4, mflag);
  const int NWORDS = MASK_N / 32;
  mask_canon_bits<<<(NWORDS + 255) / 256, 256, 0, stream>>>(mask_raw, mbits, NWORDS, mflag);

  dim3 gg(128, 8);
  gemm_bt<0, false, true><<<gg, 256, 0, stream>>>(qn, w_qs, qen, 0.125f, nullptr, nullptr);
  gemm_bt<0, false, true><<<gg, 256, 0, stream>>>(qn, w_ex, qex, 0.125f, nullptr, nullptr);
  gemm_bt<0, true,  true><<<gg, 256, 0, stream>>>(k,  w_ks, khb, 1.0f, nullptr, nullptr);
  gemm_bt<1, true,  true><<<gg, 256, 0, stream>>>(v,  w_vs, vhT, 1.0f, nullptr, nullptr);

  attn_kernel<<<dim3(16, 8, 8), 256, 0, stream>>>(qen, qex, khb, vhT, etype, mbits,
                                                  attn_g, ao);

  gemm_bt<2, false, true><<<gg, 256, 0, stream>>>(ao, w_fc, outp, 1.0f, b_fc, q);
}